// Round 1
// baseline (2709.780 us; speedup 1.0000x reference)
//
#include <hip/hip_runtime.h>
#include <hip/hip_bf16.h>

// SoftMoE fp32 baseline.
// B=4 L=2048 D=1024 H=16 S=512 E=8 FF=4096 DH=64
#define B_  4
#define L_  2048
#define D_  1024
#define H_  16
#define S_  512
#define E_  8
#define FF_ 4096
#define DH_ 64

// ---------------- LayerNorm: one block per row (1024 cols, 256 thr x float4) --
__global__ __launch_bounds__(256) void ln_kernel(const float* __restrict__ x,
    const float* __restrict__ w, const float* __restrict__ b,
    float* __restrict__ xn) {
  int row = blockIdx.x;
  int tid = threadIdx.x;
  const float4* xr = (const float4*)(x + (long)row * D_);
  float4 v = xr[tid];
  float s = v.x + v.y + v.z + v.w;
  __shared__ float red[4];
  #pragma unroll
  for (int off = 32; off > 0; off >>= 1) s += __shfl_down(s, off);
  int wid = tid >> 6, lane = tid & 63;
  if (lane == 0) red[wid] = s;
  __syncthreads();
  float mean = (red[0] + red[1] + red[2] + red[3]) * (1.0f / D_);
  __syncthreads();
  float dx = v.x - mean, dy = v.y - mean, dz = v.z - mean, dw = v.w - mean;
  float s2 = dx*dx + dy*dy + dz*dz + dw*dw;
  #pragma unroll
  for (int off = 32; off > 0; off >>= 1) s2 += __shfl_down(s2, off);
  if (lane == 0) red[wid] = s2;
  __syncthreads();
  float var = (red[0] + red[1] + red[2] + red[3]) * (1.0f / D_);
  float rstd = rsqrtf(var + 1e-5f);
  float4 wv = ((const float4*)w)[tid];
  float4 bv = ((const float4*)b)[tid];
  float4 o;
  o.x = dx * rstd * wv.x + bv.x;
  o.y = dy * rstd * wv.y + bv.y;
  o.z = dz * rstd * wv.z + bv.z;
  o.w = dw * rstd * wv.w + bv.w;
  ((float4*)(xn + (long)row * D_))[tid] = o;
}

// ---------------- Tiled fp32 GEMM: C = A * B^T (K contiguous in both) --------
// MODE 0: plain (A: MxK lda=K, C: MxN ldc=N), no epilogue.
// MODE 1: expert-in. A rows gathered from y (B,S,D); Bm=w_in[e]; out h with
//         bias+relu^2 epilogue, C stride FF.
// MODE 2: expert-out. A rows from h (B,E,64,FF); Bm=w_out[e]; out eo (B,S,D),
//         bias epilogue.
template<int MODE>
__global__ __launch_bounds__(256) void gemm_kernel(
    const float* __restrict__ A, const float* __restrict__ Bm,
    const float* __restrict__ bias, float* __restrict__ C,
    int M, int N, int K) {
  int e = blockIdx.z;
  int n0 = blockIdx.x * 128, m0 = blockIdx.y * 128;
  int tid = threadIdx.x;
  int tx = tid & 15, ty = tid >> 4;
  __shared__ float As[8][128];
  __shared__ float Bs[8][128];
  float c[8][8];
  #pragma unroll
  for (int i = 0; i < 8; ++i)
    #pragma unroll
    for (int j = 0; j < 8; ++j) c[i][j] = 0.f;

  const float* Bp = Bm;
  if (MODE == 1) Bp += (long)e * FF_ * D_;
  if (MODE == 2) Bp += (long)e * D_ * FF_;

  int lr = tid >> 1;            // tile row 0..127
  int lk = (tid & 1) * 4;       // k quad 0 or 4
  int ar = m0 + lr;
  long aoff;
  if (MODE == 0)      aoff = (long)ar * K;
  else if (MODE == 1) aoff = ((long)(ar >> 6) * 512 + e * 64 + (ar & 63)) * 1024;
  else                aoff = ((long)((ar >> 6) * 8 + e) * 64 + (ar & 63)) * 4096;
  long boff = (long)(n0 + lr) * K;

  for (int kt = 0; kt < K; kt += 8) {
    float4 av = *(const float4*)(A + aoff + kt + lk);
    float4 bv = *(const float4*)(Bp + boff + kt + lk);
    __syncthreads();
    As[lk+0][lr] = av.x; As[lk+1][lr] = av.y; As[lk+2][lr] = av.z; As[lk+3][lr] = av.w;
    Bs[lk+0][lr] = bv.x; Bs[lk+1][lr] = bv.y; Bs[lk+2][lr] = bv.z; Bs[lk+3][lr] = bv.w;
    __syncthreads();
    #pragma unroll
    for (int kk = 0; kk < 8; ++kk) {
      float4 a0 = *(const float4*)&As[kk][ty*8];
      float4 a1 = *(const float4*)&As[kk][ty*8+4];
      float4 b0 = *(const float4*)&Bs[kk][tx*8];
      float4 b1 = *(const float4*)&Bs[kk][tx*8+4];
      float a[8] = {a0.x,a0.y,a0.z,a0.w,a1.x,a1.y,a1.z,a1.w};
      float bb[8] = {b0.x,b0.y,b0.z,b0.w,b1.x,b1.y,b1.z,b1.w};
      #pragma unroll
      for (int i = 0; i < 8; ++i)
        #pragma unroll
        for (int j = 0; j < 8; ++j)
          c[i][j] = fmaf(a[i], bb[j], c[i][j]);
    }
  }

  #pragma unroll
  for (int i = 0; i < 8; ++i) {
    int row = m0 + ty*8 + i;
    long co;
    if (MODE == 0)      co = (long)row * N;
    else if (MODE == 1) co = ((long)((row >> 6) * 8 + e) * 64 + (row & 63)) * 4096;
    else                co = ((long)(row >> 6) * 512 + e * 64 + (row & 63)) * 1024;
    #pragma unroll
    for (int jq = 0; jq < 2; ++jq) {
      int col = n0 + tx*8 + jq*4;
      float t0 = c[i][jq*4+0], t1 = c[i][jq*4+1], t2 = c[i][jq*4+2], t3 = c[i][jq*4+3];
      if (MODE == 1) {
        t0 += bias[e*FF_ + col+0]; t1 += bias[e*FF_ + col+1];
        t2 += bias[e*FF_ + col+2]; t3 += bias[e*FF_ + col+3];
        t0 = fmaxf(t0, 0.f); t1 = fmaxf(t1, 0.f); t2 = fmaxf(t2, 0.f); t3 = fmaxf(t3, 0.f);
        t0 *= t0; t1 *= t1; t2 *= t2; t3 *= t3;
      } else if (MODE == 2) {
        t0 += bias[e*D_ + col+0]; t1 += bias[e*D_ + col+1];
        t2 += bias[e*D_ + col+2]; t3 += bias[e*D_ + col+3];
      }
      float4 o; o.x = t0; o.y = t1; o.z = t2; o.w = t3;
      *(float4*)(C + co + col) = o;
    }
  }
}

// ---------------- Generic flash attention (head dim 64) ----------------------
// One thread per query row; K/V tiled 128 rows through LDS; two-pass streaming
// softmax. nC>1: write per-chunk partials (m,d,acc) for a finalize pass.
__global__ __launch_bounds__(256) void flash_kernel(
    const float* __restrict__ Q, long qB, long qH, long qR,
    const float* __restrict__ Kx, long kB, long kH, long kR,
    const float* __restrict__ Vx, long vB, long vH, long vR,
    float* __restrict__ outp, long oB, long oH, long oR,
    float* __restrict__ pm, float* __restrict__ pd, float* __restrict__ pacc,
    int Nq, int Nk, int nC, int nH, float scale) {
  __shared__ float skl[128][64];
  __shared__ float svl[128][64];
  int tid = threadIdx.x;
  int bh = blockIdx.z, b = bh / nH, h = bh % nH;
  int qrow = blockIdx.x * 256 + tid;
  int chunk = Nk / nC;
  int k0 = blockIdx.y * chunk;
  const float* Qp = Q + (long)b*qB + (long)h*qH + (long)qrow*qR;
  const float* Kp = Kx + (long)b*kB + (long)h*kH;
  const float* Vp = Vx + (long)b*vB + (long)h*vH;

  float q[64];
  #pragma unroll
  for (int i = 0; i < 16; ++i) {
    float4 t = *(const float4*)(Qp + i*4);
    q[4*i+0] = t.x; q[4*i+1] = t.y; q[4*i+2] = t.z; q[4*i+3] = t.w;
  }

  // pass 1: running max + denom
  float m = -1e30f, d = 0.f;
  for (int t0 = 0; t0 < chunk; t0 += 128) {
    __syncthreads();
    #pragma unroll
    for (int f = 0; f < 8; ++f) {
      int idx = tid + f*256;
      int r = idx >> 4, c4 = (idx & 15) << 2;
      *(float4*)&skl[r][c4] = *(const float4*)(Kp + (long)(k0 + t0 + r)*kR + c4);
    }
    __syncthreads();
    for (int s = 0; s < 128; ++s) {
      float s0 = 0.f, s1 = 0.f, s2 = 0.f, s3 = 0.f;
      #pragma unroll
      for (int d4 = 0; d4 < 64; d4 += 4) {
        s0 = fmaf(q[d4+0], skl[s][d4+0], s0);
        s1 = fmaf(q[d4+1], skl[s][d4+1], s1);
        s2 = fmaf(q[d4+2], skl[s][d4+2], s2);
        s3 = fmaf(q[d4+3], skl[s][d4+3], s3);
      }
      float sc = ((s0+s1)+(s2+s3)) * scale;
      float mn = fmaxf(m, sc);
      d = d * __expf(m - mn) + __expf(sc - mn);
      m = mn;
    }
  }

  // pass 2: accumulate P*V
  float acc[64];
  #pragma unroll
  for (int i = 0; i < 64; ++i) acc[i] = 0.f;
  for (int t0 = 0; t0 < chunk; t0 += 128) {
    __syncthreads();
    #pragma unroll
    for (int f = 0; f < 8; ++f) {
      int idx = tid + f*256;
      int r = idx >> 4, c4 = (idx & 15) << 2;
      *(float4*)&skl[r][c4] = *(const float4*)(Kp + (long)(k0 + t0 + r)*kR + c4);
      *(float4*)&svl[r][c4] = *(const float4*)(Vp + (long)(k0 + t0 + r)*vR + c4);
    }
    __syncthreads();
    for (int s = 0; s < 128; ++s) {
      float s0 = 0.f, s1 = 0.f, s2 = 0.f, s3 = 0.f;
      #pragma unroll
      for (int d4 = 0; d4 < 64; d4 += 4) {
        s0 = fmaf(q[d4+0], skl[s][d4+0], s0);
        s1 = fmaf(q[d4+1], skl[s][d4+1], s1);
        s2 = fmaf(q[d4+2], skl[s][d4+2], s2);
        s3 = fmaf(q[d4+3], skl[s][d4+3], s3);
      }
      float sc = ((s0+s1)+(s2+s3)) * scale;
      float p = __expf(sc - m);
      #pragma unroll
      for (int dh = 0; dh < 64; ++dh)
        acc[dh] = fmaf(p, svl[s][dh], acc[dh]);
    }
  }

  if (nC == 1) {
    float inv = 1.0f / d;
    float* op = outp + (long)b*oB + (long)h*oH + (long)qrow*oR;
    #pragma unroll
    for (int i = 0; i < 16; ++i) {
      float4 t;
      t.x = acc[4*i+0]*inv; t.y = acc[4*i+1]*inv;
      t.z = acc[4*i+2]*inv; t.w = acc[4*i+3]*inv;
      *(float4*)(op + 4*i) = t;
    }
  } else {
    long idx = ((long)bh * Nq + qrow) * nC + blockIdx.y;
    pm[idx] = m;
    pd[idx] = d;
    #pragma unroll
    for (int i = 0; i < 64; ++i) pacc[idx*64 + i] = acc[i];
  }
}

// ---------------- Flash finalize: merge nC chunk partials per query row ------
__global__ __launch_bounds__(256) void finalize_kernel(
    const float* __restrict__ pm, const float* __restrict__ pd,
    const float* __restrict__ pacc, float* __restrict__ outp,
    int nC, int Nq, int nH, long oB, long oH, long oR) {
  int tid = threadIdx.x;
  int row = blockIdx.x * 4 + (tid >> 6);
  int lane = tid & 63;
  long base = (long)row * nC;
  float M = -1e30f;
  for (int c = 0; c < nC; ++c) M = fmaxf(M, pm[base + c]);
  float Dn = 0.f, a = 0.f;
  for (int c = 0; c < nC; ++c) {
    float w = __expf(pm[base + c] - M);
    Dn += pd[base + c] * w;
    a += pacc[(base + c)*64 + lane] * w;
  }
  int bh = row / Nq, qrow = row - bh*Nq;
  int b = bh / nH, h = bh % nH;
  outp[(long)b*oB + (long)h*oH + (long)qrow*oR + lane] = a / Dn;
}

extern "C" void kernel_launch(void* const* d_in, const int* in_sizes, int n_in,
                              void* d_out, int out_size, void* d_ws, size_t ws_size,
                              hipStream_t stream) {
  const float* x     = (const float*)d_in[0];
  const float* sq    = (const float*)d_in[1];   // slot_query (H,S,DH)
  const float* skq   = (const float*)d_in[2];   // slot_key   (H,S,DH)
  const float* wk    = (const float*)d_in[3];
  const float* wv    = (const float*)d_in[4];
  const float* wq    = (const float*)d_in[5];
  const float* w_in  = (const float*)d_in[6];
  const float* b_in  = (const float*)d_in[7];
  const float* w_out = (const float*)d_in[8];
  const float* b_out = (const float*)d_in[9];
  const float* pnw   = (const float*)d_in[10];
  const float* pnb   = (const float*)d_in[11];
  float* out = (float*)d_out;

  // ws layout (floats). peak ~152 MB.
  float* ws   = (float*)d_ws;
  float* xn   = ws;                 // 8192*1024
  float* kbuf = xn   + 8388608;     // 8192*1024 (reused as hbuf)
  float* vbuf = kbuf + 8388608;     // 8192*1024 (reused as qbuf)
  float* ybuf = vbuf + 8388608;     // 4*512*1024
  float* eob  = ybuf + 2097152;     // 4*512*1024
  float* pmb  = eob  + 2097152;     // 32768*4
  float* pdb  = pmb  + 131072;
  float* pacc = pdb  + 131072;      // 32768*4*64
  float* hbuf = kbuf;
  float* qbuf = vbuf;

  // 1. pre-norm
  ln_kernel<<<8192, 256, 0, stream>>>(x, pnw, pnb, xn);

  // 2. k, v projections
  gemm_kernel<0><<<dim3(8, 64, 1), 256, 0, stream>>>(xn, wk, nullptr, kbuf, 8192, 1024, 1024);
  gemm_kernel<0><<<dim3(8, 64, 1), 256, 0, stream>>>(xn, wv, nullptr, vbuf, 8192, 1024, 1024);

  // 3. dispatch attention: Q=slot_query (per h), K/V=tokens, split L into 4 chunks
  flash_kernel<<<dim3(2, 4, B_*H_), 256, 0, stream>>>(
      sq,   0L,              (long)(S_*DH_), (long)DH_,
      kbuf, (long)(L_*D_),   (long)DH_,      (long)D_,
      vbuf, (long)(L_*D_),   (long)DH_,      (long)D_,
      nullptr, 0L, 0L, 0L,
      pmb, pdb, pacc, S_, L_, 4, H_, 0.125f);
  finalize_kernel<<<8192, 256, 0, stream>>>(pmb, pdb, pacc, ybuf, 4, S_, H_,
      (long)(S_*D_), (long)DH_, (long)D_);

  // 4. experts: h = relu2(y @ w_in^T + b_in); eo = h @ w_out^T + b_out
  gemm_kernel<1><<<dim3(32, 2, E_), 256, 0, stream>>>(ybuf, w_in, b_in, hbuf, 256, 4096, 1024);
  gemm_kernel<2><<<dim3(8, 2, E_), 256, 0, stream>>>(hbuf, w_out, b_out, eob, 256, 1024, 4096);

  // 5. q projection
  gemm_kernel<0><<<dim3(8, 64, 1), 256, 0, stream>>>(xn, wq, nullptr, qbuf, 8192, 1024, 1024);

  // 6. combine attention: Q=tokens, K=slot_key, V=eo -> out
  flash_kernel<<<dim3(8, 1, B_*H_), 256, 0, stream>>>(
      qbuf, (long)(L_*D_),   (long)DH_,      (long)D_,
      skq,  0L,              (long)(S_*DH_), (long)DH_,
      eob,  (long)(S_*D_),   (long)DH_,      (long)D_,
      out,  (long)(L_*D_),   (long)DH_,      (long)D_,
      nullptr, nullptr, nullptr, L_, S_, 1, H_, 0.125f);
}

// Round 2
// 508.526 us; speedup vs baseline: 5.3287x; 5.3287x over previous
//
#include <hip/hip_runtime.h>
#include <hip/hip_bf16.h>

// SoftMoE fp16-MFMA pipeline. B=4 L=2048 D=1024 H=16 S=512 E=8 FF=4096 DH=64
#define B_  4
#define L_  2048
#define D_  1024
#define H_  16
#define S_  512
#define E_  8
#define FF_ 4096
#define DH_ 64

typedef _Float16 half8 __attribute__((ext_vector_type(8)));
typedef _Float16 half4v __attribute__((ext_vector_type(4)));
typedef float floatx4 __attribute__((ext_vector_type(4)));
typedef unsigned short u16;

__device__ inline u16 f2h(float v) {
  _Float16 x = (_Float16)v;
  return __builtin_bit_cast(u16, x);
}

__device__ inline void gload_lds16(const void* g, void* l) {
  __builtin_amdgcn_global_load_lds(
      (const __attribute__((address_space(1))) void*)g,
      (__attribute__((address_space(3))) void*)l, 16, 0, 0);
}

// swizzled index (u16 units): row stride 64 halfs (128B), XOR 16B granule by row&7
__device__ inline int swz(int row, int colh) {  // colh multiple of 8
  return row * 64 + (colh ^ ((row & 7) << 3));
}
__device__ inline int swz1(int row, int colh) { // arbitrary colh (scalar writes)
  return row * 64 + ((colh & ~7) ^ ((row & 7) << 3)) + (colh & 7);
}

// ---------------- LayerNorm -> fp16 ------------------------------------------
__global__ __launch_bounds__(256) void ln_f16(const float* __restrict__ x,
    const float* __restrict__ w, const float* __restrict__ bb,
    u16* __restrict__ xn) {
  int row = blockIdx.x;
  int tid = threadIdx.x;
  float4 v = ((const float4*)(x + (long)row * D_))[tid];
  float s = v.x + v.y + v.z + v.w;
  __shared__ float red[4];
  #pragma unroll
  for (int off = 32; off > 0; off >>= 1) s += __shfl_down(s, off);
  int wid = tid >> 6, lane = tid & 63;
  if (lane == 0) red[wid] = s;
  __syncthreads();
  float mean = (red[0] + red[1] + red[2] + red[3]) * (1.0f / D_);
  __syncthreads();
  float dx = v.x - mean, dy = v.y - mean, dz = v.z - mean, dw = v.w - mean;
  float s2 = dx*dx + dy*dy + dz*dz + dw*dw;
  #pragma unroll
  for (int off = 32; off > 0; off >>= 1) s2 += __shfl_down(s2, off);
  if (lane == 0) red[wid] = s2;
  __syncthreads();
  float var = (red[0] + red[1] + red[2] + red[3]) * (1.0f / D_);
  float rstd = rsqrtf(var + 1e-5f);
  float4 wv = ((const float4*)w)[tid];
  float4 bv = ((const float4*)bb)[tid];
  half4v o = { (_Float16)(dx * rstd * wv.x + bv.x),
               (_Float16)(dy * rstd * wv.y + bv.y),
               (_Float16)(dz * rstd * wv.z + bv.z),
               (_Float16)(dw * rstd * wv.w + bv.w) };
  *(half4v*)&xn[(long)row * D_ + tid * 4] = o;
}

// ---------------- fp16 MFMA GEMM: C = A * B^T --------------------------------
// A fp16 (gathered rows per MODE), B fp32 converted on the fly (N x K, K contig)
// MODE 0: plain. MODE 1: expert-in (bias+relu^2 -> h). MODE 2: expert-out (bias -> eo).
template<int MODE, int BM>
__global__ __launch_bounds__(BM == 256 ? 512 : 256) void gemm_f16(
    const u16* __restrict__ A, const float* __restrict__ Bw,
    const float* __restrict__ bias, u16* __restrict__ C, int N, int K) {
  constexpr int NW = (BM == 256) ? 8 : 4;    // waves
  const int e  = blockIdx.z;
  const int n0 = blockIdx.x * 128, m0 = blockIdx.y * BM;
  const int tid = threadIdx.x, l = tid & 63, w = tid >> 6;
  const int wr = w >> 1, wc = w & 1;
  __shared__ __align__(16) u16 As[BM * 32];
  __shared__ __align__(16) u16 Bs[128 * 32];
  floatx4 acc[4][4] = {};

  // A: wave stages rows [w*32, w*32+32), 2 x global_load_lds(16B)
  long ga[2];
  #pragma unroll
  for (int i = 0; i < 2; ++i) {
    int ar = m0 + w * 32 + i * 16 + (l >> 2);
    long grow;
    if (MODE == 0)      grow = ar;
    else if (MODE == 1) grow = (long)(ar >> 6) * 512 + e * 64 + (ar & 63);
    else                grow = ((long)(ar >> 6) * 8 + e) * 64 + (ar & 63);
    ga[i] = grow * (long)K + (l & 3) * 8;
  }
  const float* Bp = Bw + (MODE == 1 ? (long)e * FF_ * D_
                        : (MODE == 2 ? (long)e * D_ * FF_ : 0L));
  constexpr int BROWS = 128 / NW;   // rows of B staged per wave
  constexpr int BI = BROWS / 8;     // float4-load instructions per wave
  const int brow0 = w * BROWS;

  for (int kt = 0; kt < K; kt += 32) {
    gload_lds16(A + ga[0] + kt, &As[(w * 32) * 32]);
    gload_lds16(A + ga[1] + kt, &As[(w * 32 + 16) * 32]);
    float4 bf[BI];
    #pragma unroll
    for (int i = 0; i < BI; ++i) {
      int rr = brow0 + i * 8 + (l >> 3);
      bf[i] = *(const float4*)(Bp + (long)(n0 + rr) * K + kt + (l & 7) * 4);
    }
    #pragma unroll
    for (int i = 0; i < BI; ++i) {
      int rr = brow0 + i * 8 + (l >> 3);
      half4v hv = { (_Float16)bf[i].x, (_Float16)bf[i].y,
                    (_Float16)bf[i].z, (_Float16)bf[i].w };
      int g = (l & 7) >> 1;
      int idx = rr * 32 + (((g ^ (rr & 3))) << 3) + (l & 1) * 4;
      *(half4v*)&Bs[idx] = hv;
    }
    __syncthreads();
    half8 af[4], bfr[4];
    #pragma unroll
    for (int fr = 0; fr < 4; ++fr)
      af[fr] = *(const half8*)&As[(wr * 64 + fr * 16 + (l & 15)) * 32 + (l >> 4) * 8];
    #pragma unroll
    for (int fc = 0; fc < 4; ++fc) {
      int rr = wc * 64 + fc * 16 + (l & 15);
      bfr[fc] = *(const half8*)&Bs[rr * 32 + (((l >> 4) ^ (rr & 3)) << 3)];
    }
    #pragma unroll
    for (int fr = 0; fr < 4; ++fr)
      #pragma unroll
      for (int fc = 0; fc < 4; ++fc)
        acc[fr][fc] = __builtin_amdgcn_mfma_f32_16x16x32_f16(af[fr], bfr[fc], acc[fr][fc], 0, 0, 0);
    __syncthreads();
  }

  #pragma unroll
  for (int fr = 0; fr < 4; ++fr)
    #pragma unroll
    for (int fc = 0; fc < 4; ++fc)
      #pragma unroll
      for (int r = 0; r < 4; ++r) {
        int row = m0 + wr * 64 + fr * 16 + (l >> 4) * 4 + r;
        int col = n0 + wc * 64 + fc * 16 + (l & 15);
        float val = acc[fr][fc][r];
        if constexpr (MODE == 0) {
          C[(long)row * N + col] = f2h(val);
        } else if constexpr (MODE == 1) {
          val += bias[e * FF_ + col];
          val = fmaxf(val, 0.f);
          val *= val;
          long hrow = ((long)(row >> 6) * 8 + e) * 64 + (row & 63);
          C[hrow * FF_ + col] = f2h(val);
        } else {
          val += bias[e * D_ + col];
          long erow = (long)(row >> 6) * 512 + e * 64 + (row & 63);
          C[erow * D_ + col] = f2h(val);
        }
      }
}

// ---------------- MFMA flash attention (DH=64, 64-Q tile, 64-key tiles) ------
// 4 waves; wave owns 16 q-rows. K LDS swizzled row-major; V LDS transposed
// (dh-major) swizzled; P bounced via wave-private swizzled LDS.
template<bool QF32, bool KF32, bool OF32>
__global__ __launch_bounds__(256) void flash_f16(
    const void* __restrict__ Qv, long qB, long qH, long qR,
    const void* __restrict__ Kv, long kB, long kH, long kR,
    const u16* __restrict__ Vg, long vB, long vH, long vR,
    void* __restrict__ Og, long oB, long oH, long oR,
    int Nk, float scale) {
  __shared__ __align__(16) u16 Ks[64 * 64];
  __shared__ __align__(16) u16 Vt[64 * 64];
  __shared__ __align__(16) u16 Ps[4][16 * 64];
  const int tid = threadIdx.x, l = tid & 63, w = tid >> 6;
  const int bh = blockIdx.z, b = bh >> 4, hd = bh & 15;
  const int q0 = blockIdx.x * 64 + w * 16;

  // Q fragments (held in registers for entire kernel)
  half8 qf[2];
  #pragma unroll
  for (int ks = 0; ks < 2; ++ks) {
    long qoff = b * qB + hd * qH + (long)(q0 + (l & 15)) * qR + ks * 32 + (l >> 4) * 8;
    if (QF32) {
      const float* qp = (const float*)Qv + qoff;
      float4 a = *(const float4*)qp, c = *(const float4*)(qp + 4);
      qf[ks] = (half8){ (_Float16)a.x, (_Float16)a.y, (_Float16)a.z, (_Float16)a.w,
                        (_Float16)c.x, (_Float16)c.y, (_Float16)c.z, (_Float16)c.w };
    } else {
      qf[ks] = *(const half8*)((const u16*)Qv + qoff);
    }
  }

  float mrun[4] = { -1e30f, -1e30f, -1e30f, -1e30f };
  float lrun[4] = { 0.f, 0.f, 0.f, 0.f };
  floatx4 o[4] = {};

  const int sr = tid & 63, cc = tid >> 6;   // staging: row, 16-half column chunk

  for (int t = 0; t < Nk; t += 64) {
    // ---- stage K tile (64 keys x 64 dh), swizzled ----
    if (!KF32) {
      const u16* ksrc = (const u16*)Kv + b * kB + hd * kH + (long)(t + sr) * kR + cc * 16;
      *(uint4*)&Ks[swz(sr, cc * 16)]     = *(const uint4*)ksrc;
      *(uint4*)&Ks[swz(sr, cc * 16 + 8)] = *(const uint4*)(ksrc + 8);
    } else {
      const float* ksrc = (const float*)Kv + b * kB + hd * kH + (long)(t + sr) * kR + cc * 16;
      float4 f0 = *(const float4*)ksrc,     f1 = *(const float4*)(ksrc + 4);
      float4 f2 = *(const float4*)(ksrc + 8), f3 = *(const float4*)(ksrc + 12);
      half8 h0 = { (_Float16)f0.x, (_Float16)f0.y, (_Float16)f0.z, (_Float16)f0.w,
                   (_Float16)f1.x, (_Float16)f1.y, (_Float16)f1.z, (_Float16)f1.w };
      half8 h1 = { (_Float16)f2.x, (_Float16)f2.y, (_Float16)f2.z, (_Float16)f2.w,
                   (_Float16)f3.x, (_Float16)f3.y, (_Float16)f3.z, (_Float16)f3.w };
      *(half8*)&Ks[swz(sr, cc * 16)]     = h0;
      *(half8*)&Ks[swz(sr, cc * 16 + 8)] = h1;
    }
    // ---- stage V tile transposed (dh-major), swizzled ----
    {
      const u16* vsrc = Vg + b * vB + hd * vH + (long)(t + sr) * vR + cc * 16;
      #pragma unroll
      for (int c2 = 0; c2 < 2; ++c2) {
        uint4 dv = *(const uint4*)(vsrc + c2 * 8);
        const u16* pv = (const u16*)&dv;
        #pragma unroll
        for (int i = 0; i < 8; ++i) {
          int dh = cc * 16 + c2 * 8 + i;
          Vt[swz1(dh, sr)] = pv[i];
        }
      }
    }
    __syncthreads();

    // ---- scores: S = Q K^T (16q x 64key per wave) ----
    floatx4 s[4];
    #pragma unroll
    for (int j = 0; j < 4; ++j) s[j] = (floatx4){0.f, 0.f, 0.f, 0.f};
    #pragma unroll
    for (int ks = 0; ks < 2; ++ks)
      #pragma unroll
      for (int j = 0; j < 4; ++j) {
        int kr = j * 16 + (l & 15);
        half8 kf = *(const half8*)&Ks[swz(kr, ks * 32 + (l >> 4) * 8)];
        s[j] = __builtin_amdgcn_mfma_f32_16x16x32_f16(qf[ks], kf, s[j], 0, 0, 0);
      }

    // ---- online softmax (rows spread over reg r; cols over lanes&15) ----
    #pragma unroll
    for (int r = 0; r < 4; ++r) {
      float m4 = fmaxf(fmaxf(s[0][r], s[1][r]), fmaxf(s[2][r], s[3][r]));
      m4 = fmaxf(m4, __shfl_xor(m4, 1));
      m4 = fmaxf(m4, __shfl_xor(m4, 2));
      m4 = fmaxf(m4, __shfl_xor(m4, 4));
      m4 = fmaxf(m4, __shfl_xor(m4, 8));
      m4 *= scale;
      float mnew = fmaxf(mrun[r], m4);
      float corr = __expf(mrun[r] - mnew);
      float rs = 0.f;
      int q = (l >> 4) * 4 + r;
      #pragma unroll
      for (int j = 0; j < 4; ++j) {
        float p = __expf(s[j][r] * scale - mnew);
        rs += p;
        Ps[w][swz1(q, j * 16 + (l & 15))] = f2h(p);
      }
      rs += __shfl_xor(rs, 1);
      rs += __shfl_xor(rs, 2);
      rs += __shfl_xor(rs, 4);
      rs += __shfl_xor(rs, 8);
      lrun[r] = lrun[r] * corr + rs;
      mrun[r] = mnew;
      o[0][r] *= corr; o[1][r] *= corr; o[2][r] *= corr; o[3][r] *= corr;
    }

    // ---- PV: O += P V (contraction over 64 keys) ----
    #pragma unroll
    for (int ks = 0; ks < 2; ++ks) {
      half8 pa = *(const half8*)&Ps[w][swz(l & 15, ks * 32 + (l >> 4) * 8)];
      #pragma unroll
      for (int n = 0; n < 4; ++n) {
        int dr = n * 16 + (l & 15);
        half8 vf = *(const half8*)&Vt[swz(dr, ks * 32 + (l >> 4) * 8)];
        o[n] = __builtin_amdgcn_mfma_f32_16x16x32_f16(pa, vf, o[n], 0, 0, 0);
      }
    }
    __syncthreads();
  }

  // ---- epilogue ----
  float inv[4];
  #pragma unroll
  for (int r = 0; r < 4; ++r) inv[r] = 1.0f / lrun[r];
  #pragma unroll
  for (int n = 0; n < 4; ++n)
    #pragma unroll
    for (int r = 0; r < 4; ++r) {
      int row = q0 + (l >> 4) * 4 + r;
      int dh = n * 16 + (l & 15);
      float val = o[n][r] * inv[r];
      long off = b * oB + hd * oH + (long)row * oR + dh;
      if (OF32) ((float*)Og)[off] = val;
      else      ((u16*)Og)[off] = f2h(val);
    }
}

extern "C" void kernel_launch(void* const* d_in, const int* in_sizes, int n_in,
                              void* d_out, int out_size, void* d_ws, size_t ws_size,
                              hipStream_t stream) {
  const float* x     = (const float*)d_in[0];
  const float* sq    = (const float*)d_in[1];   // slot_query (H,S,DH) f32
  const float* skq   = (const float*)d_in[2];   // slot_key   (H,S,DH) f32
  const float* wk    = (const float*)d_in[3];
  const float* wv    = (const float*)d_in[4];
  const float* wq    = (const float*)d_in[5];
  const float* w_in  = (const float*)d_in[6];
  const float* b_in  = (const float*)d_in[7];
  const float* w_out = (const float*)d_in[8];
  const float* b_out = (const float*)d_in[9];
  const float* pnw   = (const float*)d_in[10];
  const float* pnb   = (const float*)d_in[11];
  float* out = (float*)d_out;

  // ws layout (u16 units), total ~92 MB
  u16* ws  = (u16*)d_ws;
  u16* xnh = ws;                  // 8192*1024
  u16* kh  = xnh + 8388608;       // 8192*1024
  u16* vh  = kh  + 8388608;       // 8192*1024
  u16* qh  = vh  + 8388608;       // 8192*1024
  u16* yh  = qh  + 8388608;       // 4*512*1024
  u16* hh  = yh  + 2097152;       // 2048*4096
  u16* eoh = hh  + 8388608;       // 4*512*1024

  // 1. pre-norm -> fp16
  ln_f16<<<8192, 256, 0, stream>>>(x, pnw, pnb, xnh);

  // 2. projections k, v (fp16 MFMA, weights cvt on the fly)
  gemm_f16<0, 128><<<dim3(8, 64, 1), 256, 0, stream>>>(xnh, wk, nullptr, kh, D_, D_);
  gemm_f16<0, 128><<<dim3(8, 64, 1), 256, 0, stream>>>(xnh, wv, nullptr, vh, D_, D_);

  // 3. dispatch attention: Q=slot_query(f32), K/V=tokens(f16) -> y (f16)
  flash_f16<true, false, false><<<dim3(8, 1, 64), 256, 0, stream>>>(
      sq, 0L, (long)(S_ * DH_), (long)DH_,
      kh, (long)(L_ * D_), (long)DH_, (long)D_,
      vh, (long)(L_ * D_), (long)DH_, (long)D_,
      yh, (long)(S_ * D_), (long)DH_, (long)D_,
      L_, 0.125f);

  // 4. experts
  gemm_f16<1, 256><<<dim3(32, 1, 8), 512, 0, stream>>>(yh, w_in, b_in, hh, FF_, D_);
  gemm_f16<2, 128><<<dim3(8, 2, 8), 256, 0, stream>>>(hh, w_out, b_out, eoh, D_, FF_);

  // 5. q projection
  gemm_f16<0, 128><<<dim3(8, 64, 1), 256, 0, stream>>>(xnh, wq, nullptr, qh, D_, D_);

  // 6. combine attention: Q=tokens(f16), K=slot_key(f32), V=eo(f16) -> out f32
  flash_f16<false, true, true><<<dim3(32, 1, 64), 256, 0, stream>>>(
      qh, (long)(L_ * D_), (long)DH_, (long)D_,
      skq, 0L, (long)(S_ * DH_), (long)DH_,
      eoh, (long)(S_ * D_), (long)DH_, (long)D_,
      out, (long)(L_ * D_), (long)DH_, (long)D_,
      S_, 0.125f);
}